// Round 1
// baseline (3668.517 us; speedup 1.0000x reference)
//
#include <hip/hip_runtime.h>
#include <math.h>

#define TEMPC 0.0005f

constexpr int BB  = 32;
constexpr int TEN = 512;
constexpr int TDE = 2048;
constexpr int CQ  = 80;
constexpr int CK  = 512;
constexpr int CA  = 128;

// ---------------------------------------------------------------------------
// Weight transpose: src [OC][IC][KK] -> dst [KK*IC][OC]  (k = dt*IC + ic)
// ---------------------------------------------------------------------------
__global__ void transpose_w(const float* __restrict__ src, float* __restrict__ dst,
                            int IC, int OC, int KK) {
  int total = IC * OC * KK;
  for (int i = blockIdx.x * blockDim.x + threadIdx.x; i < total;
       i += gridDim.x * blockDim.x) {
    int oc = i % OC;
    int k  = i / OC;
    int dt = k / IC;
    int ic = k - dt * IC;
    dst[i] = src[(oc * IC + ic) * KK + dt];
  }
}

// ---------------------------------------------------------------------------
// fp32 tiled GEMM: C[M][N] = op(A)[M][K] @ Bw[K][N] + bias (opt relu)
// IM2COL: A element [p][k] = src[p*Cin + k - Cin], zero-padded at t edges
//         (row p = b*T + t; k = dt*Cin + ic; valid iff 0 <= t+dt-1 < T)
// Tile 64x64, BK=16, 256 threads, 4x4 per thread.
// ---------------------------------------------------------------------------
template<bool IM2COL, bool RELU>
__global__ void gemm_k(const float* __restrict__ A, const float* __restrict__ Bw,
                       const float* __restrict__ bias, float* __restrict__ C,
                       int M, int N, int K, int Cin, int T) {
  __shared__ float As[16][65];
  __shared__ float Bs[16][68];
  const int tid = threadIdx.x;
  const int tm = tid >> 4, tn = tid & 15;
  const int m0 = blockIdx.x * 64, n0 = blockIdx.y * 64;
  const int la_m = tid >> 2, la_k = (tid & 3) * 4;
  const int lb_k = tid >> 4, lb_n = (tid & 15) * 4;
  const int p = m0 + la_m;
  int t = 0;
  if constexpr (IM2COL) t = p % T;

  float acc[4][4] = {};
  for (int k0 = 0; k0 < K; k0 += 16) {
#pragma unroll
    for (int i = 0; i < 4; ++i) {
      int k = k0 + la_k + i;
      float v;
      if constexpr (IM2COL) {
        int dt = (k >= Cin) + (k >= 2 * Cin);
        int tt = t + dt - 1;
        v = (tt >= 0 && tt < T) ? A[(long)p * Cin + (k - Cin)] : 0.f;
      } else {
        v = A[(long)p * K + k];
      }
      As[la_k + i][la_m] = v;
    }
#pragma unroll
    for (int i = 0; i < 4; ++i) {
      int n = n0 + lb_n + i;
      Bs[lb_k][lb_n + i] = (n < N) ? Bw[(long)(k0 + lb_k) * N + n] : 0.f;
    }
    __syncthreads();
#pragma unroll
    for (int kk = 0; kk < 16; ++kk) {
      float a[4], b[4];
#pragma unroll
      for (int i = 0; i < 4; ++i) a[i] = As[kk][tm * 4 + i];
#pragma unroll
      for (int j = 0; j < 4; ++j) b[j] = Bs[kk][tn * 4 + j];
#pragma unroll
      for (int i = 0; i < 4; ++i)
#pragma unroll
        for (int j = 0; j < 4; ++j) acc[i][j] += a[i] * b[j];
    }
    __syncthreads();
  }

  const int ncol = n0 + tn * 4;           // N is always a multiple of 4 here
  if (ncol < N) {
    float bv[4];
#pragma unroll
    for (int j = 0; j < 4; ++j) bv[j] = bias[ncol + j];
#pragma unroll
    for (int i = 0; i < 4; ++i) {
      int m = m0 + tm * 4 + i;
      float4 v;
      float* vv = (float*)&v;
#pragma unroll
      for (int j = 0; j < 4; ++j) {
        float u = acc[i][j] + bv[j];
        if constexpr (RELU) u = fmaxf(u, 0.f);
        vv[j] = u;
      }
      *(float4*)(C + (long)m * N + ncol) = v;
    }
  }
}

// ---------------------------------------------------------------------------
// Row squared-norms: dst[row] = sum_c src[row][c]^2  (128 channels, wave/row)
// ---------------------------------------------------------------------------
__global__ void norms_k(const float* __restrict__ src, float* __restrict__ dst,
                        int rows) {
  int gw = (blockIdx.x * blockDim.x + threadIdx.x) >> 6;
  int lane = threadIdx.x & 63;
  if (gw >= rows) return;
  const float* r = src + (long)gw * 128;
  float a = r[lane], b = r[lane + 64];
  float s = a * a + b * b;
#pragma unroll
  for (int o = 32; o; o >>= 1) s += __shfl_xor(s, o);
  if (lane == 0) dst[gw] = s;
}

// ---------------------------------------------------------------------------
// Logits: L0[b][t][s] = -TEMP * (|q_bt|^2 + |k_bs|^2 - 2 q.k)
// Per-batch GEMM M=2048 N=512 K=128, tile 64x64x16.
// ---------------------------------------------------------------------------
__global__ void dist_k(const float* __restrict__ q, const float* __restrict__ kmat,
                       const float* __restrict__ q2, const float* __restrict__ k2,
                       float* __restrict__ L0) {
  __shared__ float As[16][65];
  __shared__ float Bs[16][65];
  const int b = blockIdx.z;
  const int tid = threadIdx.x;
  const int tm = tid >> 4, tn = tid & 15;
  const int m0 = blockIdx.x * 64, n0 = blockIdx.y * 64;
  const int la_m = tid >> 2, la_k = (tid & 3) * 4;
  const float* A  = q    + (long)b * TDE * CA;
  const float* Bm = kmat + (long)b * TEN * CA;

  float acc[4][4] = {};
  for (int k0 = 0; k0 < CA; k0 += 16) {
#pragma unroll
    for (int i = 0; i < 4; ++i)
      As[la_k + i][la_m] = A[(long)(m0 + la_m) * CA + k0 + la_k + i];
#pragma unroll
    for (int i = 0; i < 4; ++i)
      Bs[la_k + i][la_m] = Bm[(long)(n0 + la_m) * CA + k0 + la_k + i];
    __syncthreads();
#pragma unroll
    for (int kk = 0; kk < 16; ++kk) {
      float a[4], bb[4];
#pragma unroll
      for (int i = 0; i < 4; ++i) a[i] = As[kk][tm * 4 + i];
#pragma unroll
      for (int j = 0; j < 4; ++j) bb[j] = Bs[kk][tn * 4 + j];
#pragma unroll
      for (int i = 0; i < 4; ++i)
#pragma unroll
        for (int j = 0; j < 4; ++j) acc[i][j] += a[i] * bb[j];
    }
    __syncthreads();
  }

  float q2v[4], k2v[4];
#pragma unroll
  for (int i = 0; i < 4; ++i) q2v[i] = q2[b * TDE + m0 + tm * 4 + i];
#pragma unroll
  for (int j = 0; j < 4; ++j) k2v[j] = k2[b * TEN + n0 + tn * 4 + j];
#pragma unroll
  for (int i = 0; i < 4; ++i) {
    float4 v;
    float* vv = (float*)&v;
#pragma unroll
    for (int j = 0; j < 4; ++j)
      vv[j] = -TEMPC * (q2v[i] + k2v[j] - 2.f * acc[i][j]);
    *(float4*)(L0 + ((long)(b * TDE + m0 + tm * 4 + i) * TEN) + n0 + tn * 4) = v;
  }
}

// ---------------------------------------------------------------------------
// Softmax stage: per 16-row tile (one batch):
//   lse1 = logsumexp_s(L0);  alp = L0 - lse1 + log(prior[b][s][t] + 1e-8)
//   out0 = alp;  out1 = softmax_s(alp)
// Priors staged through LDS in 16t x 256s half-tiles for coalescing.
// ---------------------------------------------------------------------------
__global__ void softmax_k(float* __restrict__ out0, float* __restrict__ out1,
                          const float* __restrict__ priors) {
  __shared__ float Ls[16][513];
  __shared__ float Ps[16][257];
  __shared__ float red1[16];
  __shared__ float red2[16];
  const int b = blockIdx.y;
  const int t0 = blockIdx.x * 16;
  const int tid = threadIdx.x;       // 256
  const long base = ((long)b * TDE + t0) * TEN;

  for (int i = tid; i < 16 * 512; i += 256) Ls[i >> 9][i & 511] = out0[base + i];
  __syncthreads();

  const int wave = tid >> 6, lane = tid & 63;
#pragma unroll
  for (int rr = 0; rr < 4; ++rr) {
    int r = wave * 4 + rr;
    float m = -INFINITY;
    for (int i = 0; i < 8; ++i) m = fmaxf(m, Ls[r][lane + 64 * i]);
    for (int o = 32; o; o >>= 1) m = fmaxf(m, __shfl_xor(m, o));
    float sum = 0.f;
    for (int i = 0; i < 8; ++i) sum += expf(Ls[r][lane + 64 * i] - m);
    for (int o = 32; o; o >>= 1) sum += __shfl_xor(sum, o);
    if (lane == 0) red1[r] = m + logf(sum);
  }
  __syncthreads();

  // two s-halves: stage priors (coalesced: 16 consecutive t = 64B), transform
  for (int h = 0; h < 2; ++h) {
    for (int i = tid; i < 16 * 256; i += 256) {
      int s = (i >> 4) + h * 256, tt = i & 15;
      Ps[tt][i >> 4] = priors[((long)b * TEN + s) * TDE + t0 + tt];
    }
    __syncthreads();
    for (int i = tid; i < 16 * 256; i += 256) {
      int r = i >> 8, sl = i & 255, s = sl + h * 256;
      float alp = Ls[r][s] - red1[r] + logf(Ps[r][sl] + 1e-8f);
      Ls[r][s] = alp;
      out0[base + r * 512 + s] = alp;
    }
    __syncthreads();
  }

#pragma unroll
  for (int rr = 0; rr < 4; ++rr) {
    int r = wave * 4 + rr;
    float m = -INFINITY;
    for (int i = 0; i < 8; ++i) m = fmaxf(m, Ls[r][lane + 64 * i]);
    for (int o = 32; o; o >>= 1) m = fmaxf(m, __shfl_xor(m, o));
    float sum = 0.f;
    for (int i = 0; i < 8; ++i) sum += expf(Ls[r][lane + 64 * i] - m);
    for (int o = 32; o; o >>= 1) sum += __shfl_xor(sum, o);
    if (lane == 0) red2[r] = m + logf(sum);
  }
  __syncthreads();

  for (int i = tid; i < 16 * 512; i += 256) {
    int r = i >> 9, s = i & 511;
    out1[base + i] = expf(Ls[r][s] - red2[r]);
  }
}

// ---------------------------------------------------------------------------
// Monotonic alignment search. One wave per batch; lane owns x in [8L, 8L+8).
// Forward: 2048 steps, neighbor exchange = single shfl_up (no barriers).
// Dirs (1 bit per x) packed 8/lane/step -> global (64B/step, coalesced).
// Backward: serial pointer-chase on lane 0 (dirs are L2-resident).
// Exactly mirrors reference semantics incl. (-inf >= -inf) == true.
// ---------------------------------------------------------------------------
__global__ void __launch_bounds__(64) mas_k(const float* __restrict__ attn,
                                            unsigned char* __restrict__ dirs,
                                            int* __restrict__ pathidx) {
  const int b = blockIdx.x;
  const int lane = threadIdx.x;
  float v[8];
#pragma unroll
  for (int i = 0; i < 8; ++i) v[i] = 0.f;
  const float* arow = attn + (long)b * TDE * TEN + lane * 8;
  unsigned char* drow = dirs + (long)b * TDE * 64;
  const int xbase = lane * 8;

  for (int j = 0; j < TDE; ++j) {
    const float4 a0 = *(const float4*)(arow + (long)j * TEN);
    const float4 a1 = *(const float4*)(arow + (long)j * TEN + 4);
    float a[8] = {a0.x, a0.y, a0.z, a0.w, a1.x, a1.y, a1.z, a1.w};
    float prev = __shfl_up(v[7], 1);
    if (lane == 0) prev = -INFINITY;
    unsigned dir = 0;
    float carry = prev;
#pragma unroll
    for (int i = 0; i < 8; ++i) {
      float v0 = carry;                 // OLD v[x-1]
      carry = v[i];                     // save OLD v[x] for next i
      bool mm = v[i] >= v0;             // -inf >= -inf -> true, as in jnp
      float vmax = mm ? v[i] : v0;
      dir |= ((unsigned)mm) << i;
      v[i] = (xbase + i <= j) ? (vmax + a[i]) : -INFINITY;
    }
    drow[j * 64 + lane] = (unsigned char)dir;
  }
  __syncthreads();

  if (lane == 0) {
    int idx = TEN - 1;                  // index0 = 511 (mask all ones)
    for (int j = TDE - 1; j >= 0; --j) {
      pathidx[b * TDE + j] = idx;       // onehot recorded BEFORE update
      int d = (drow[j * 64 + (idx >> 3)] >> (idx & 7)) & 1;
      idx += d - 1;
      if (idx < 0) idx = 0;             // safety clamp (unreachable)
    }
  }
}

// ---------------------------------------------------------------------------
// out2[b][t][s] = (s == pathidx[b][t]) as float (mas transposed)
// ---------------------------------------------------------------------------
__global__ void onehot_k(const int* __restrict__ pathidx, float* __restrict__ out2) {
  long idx = (long)blockIdx.x * blockDim.x + threadIdx.x;
  const long total4 = (long)BB * TDE * TEN / 4;
  if (idx >= total4) return;
  long row = idx >> 7;                  // 128 float4 per 512-wide row
  int s0 = (int)(idx & 127) * 4;
  int p = pathidx[row];
  float4 v;
  v.x = (s0 == p) ? 1.f : 0.f;
  v.y = (s0 + 1 == p) ? 1.f : 0.f;
  v.z = (s0 + 2 == p) ? 1.f : 0.f;
  v.w = (s0 + 3 == p) ? 1.f : 0.f;
  ((float4*)out2)[idx] = v;
}

// ---------------------------------------------------------------------------
// durations[b][x] = #{ j : pathidx[b][j] == x }  (written as float)
// ---------------------------------------------------------------------------
__global__ void dur_k(const int* __restrict__ pathidx, float* __restrict__ out3) {
  __shared__ int cnt[TEN];
  const int b = blockIdx.x, tid = threadIdx.x;   // 512 threads
  cnt[tid] = 0;
  __syncthreads();
  for (int j = tid; j < TDE; j += 512) atomicAdd(&cnt[pathidx[b * TDE + j]], 1);
  __syncthreads();
  out3[b * TEN + tid] = (float)cnt[tid];
}

// ---------------------------------------------------------------------------
extern "C" void kernel_launch(void* const* d_in, const int* in_sizes, int n_in,
                              void* d_out, int out_size, void* d_ws, size_t ws_size,
                              hipStream_t stream) {
  (void)in_sizes; (void)n_in; (void)out_size; (void)ws_size;
  const float* x      = (const float*)d_in[0];   // [B, T_EN, C_K]
  const float* y      = (const float*)d_in[1];   // [B, T_DE, C_Q]
  const float* priors = (const float*)d_in[4];   // [B, T_EN, T_DE]
  const float* kw1 = (const float*)d_in[5];
  const float* kb1 = (const float*)d_in[6];
  const float* kw2 = (const float*)d_in[7];
  const float* kb2 = (const float*)d_in[8];
  const float* qw1 = (const float*)d_in[9];
  const float* qb1 = (const float*)d_in[10];
  const float* qw2 = (const float*)d_in[11];
  const float* qb2 = (const float*)d_in[12];
  const float* qw3 = (const float*)d_in[13];
  const float* qb3 = (const float*)d_in[14];

  const long OSZ = (long)BB * TDE * TEN;       // 33,554,432
  float* out0 = (float*)d_out;                  // attn_logp
  float* out1 = out0 + OSZ;                     // attn
  float* out2 = out1 + OSZ;                     // mas^T
  float* out3 = out2 + OSZ;                     // durations (as float)

  char* ws = (char*)d_ws;
  float* wk1t = (float*)(ws + 0);               // [1536][1024]  6,291,456 B
  float* wk2t = (float*)(ws + 6291456);         // [1024][128]     524,288 B
  float* wq1t = (float*)(ws + 6815744);         // [240][160]      153,600 B
  float* wq2t = (float*)(ws + 6969344);         // [160][80]        51,200 B
  float* wq3t = (float*)(ws + 7020544);         // [80][128]        40,960 B
  float* kbuf = (float*)(ws + 7061504);         // [16384][128]  8,388,608 B
  float* qbuf = (float*)(ws + 15450112);        // [65536][128] 33,554,432 B
  float* q2   = (float*)(ws + 49004544);        //               262,144 B
  float* k2   = (float*)(ws + 49266688);        //                65,536 B
  int*   pidx = (int*)(ws + 49332224);          //               262,144 B
  unsigned char* dirs = (unsigned char*)(ws + 49594368); //    4,194,304 B
  float* hk   = (float*)(ws + 53788672);        // [16384][1024] 67,108,864 B
  float* hq1  = hk;                             // reused after hk consumed
  float* qmid = (float*)(ws + 53788672 + 41943040);
  // total ws usage: 120,897,536 B

  // weight transposes
  transpose_w<<<dim3(1024), dim3(256), 0, stream>>>(kw1, wk1t, CK, 2 * CK, 3);
  transpose_w<<<dim3(512),  dim3(256), 0, stream>>>(kw2, wk2t, 2 * CK, CA, 1);
  transpose_w<<<dim3(150),  dim3(256), 0, stream>>>(qw1, wq1t, CQ, 2 * CQ, 3);
  transpose_w<<<dim3(50),   dim3(256), 0, stream>>>(qw2, wq2t, 2 * CQ, CQ, 1);
  transpose_w<<<dim3(40),   dim3(256), 0, stream>>>(qw3, wq3t, CQ, CA, 1);

  // key path: conv1(K=3, relu at store) -> conv2(1x1) -> kbuf [b][s][128]
  gemm_k<true, true><<<dim3(16384 / 64, 16), dim3(256), 0, stream>>>(
      x, wk1t, kb1, hk, 16384, 1024, 1536, CK, TEN);
  gemm_k<false, false><<<dim3(16384 / 64, 2), dim3(256), 0, stream>>>(
      hk, wk2t, kb2, kbuf, 16384, 128, 1024, 0, 0);

  // query path: conv1(K=3,relu) -> conv2(1x1,relu) -> conv3(1x1) -> qbuf
  gemm_k<true, true><<<dim3(65536 / 64, 3), dim3(256), 0, stream>>>(
      y, wq1t, qb1, hq1, 65536, 160, 240, CQ, TDE);
  gemm_k<false, true><<<dim3(65536 / 64, 2), dim3(256), 0, stream>>>(
      hq1, wq2t, qb2, qmid, 65536, 80, 160, 0, 0);
  gemm_k<false, false><<<dim3(65536 / 64, 2), dim3(256), 0, stream>>>(
      qmid, wq3t, qb3, qbuf, 65536, 128, 80, 0, 0);

  // squared norms
  norms_k<<<dim3(65536 / 4), dim3(256), 0, stream>>>(qbuf, q2, 65536);
  norms_k<<<dim3(16384 / 4), dim3(256), 0, stream>>>(kbuf, k2, 16384);

  // logits into out0
  dist_k<<<dim3(32, 8, 32), dim3(256), 0, stream>>>(qbuf, kbuf, q2, k2, out0);

  // log-softmax + prior + softmax -> out0 (attn_logp), out1 (attn)
  softmax_k<<<dim3(128, 32), dim3(256), 0, stream>>>(out0, out1, priors);

  // monotonic alignment search
  mas_k<<<dim3(32), dim3(64), 0, stream>>>(out1, dirs, pidx);

  // outputs 2 & 3
  onehot_k<<<dim3(32768), dim3(256), 0, stream>>>(pidx, out2);
  dur_k<<<dim3(32), dim3(512), 0, stream>>>(pidx, out3);
}

// Round 2
// 1993.488 us; speedup vs baseline: 1.8403x; 1.8403x over previous
//
#include <hip/hip_runtime.h>
#include <math.h>

#define TEMPC 0.0005f

constexpr int BB  = 32;
constexpr int TEN = 512;
constexpr int TDE = 2048;
constexpr int CQ  = 80;
constexpr int CK  = 512;
constexpr int CA  = 128;

// ---------------------------------------------------------------------------
// Weight transpose: src [OC][IC][KK] -> dst [KK*IC][OC]  (k = dt*IC + ic)
// ---------------------------------------------------------------------------
__global__ void transpose_w(const float* __restrict__ src, float* __restrict__ dst,
                            int IC, int OC, int KK) {
  int total = IC * OC * KK;
  for (int i = blockIdx.x * blockDim.x + threadIdx.x; i < total;
       i += gridDim.x * blockDim.x) {
    int oc = i % OC;
    int k  = i / OC;
    int dt = k / IC;
    int ic = k - dt * IC;
    dst[i] = src[(oc * IC + ic) * KK + dt];
  }
}

// ---------------------------------------------------------------------------
// fp32 tiled GEMM 64x64 (small-N path): C = op(A) @ Bw + bias (opt relu)
// ---------------------------------------------------------------------------
template<bool IM2COL, bool RELU>
__global__ void gemm_k(const float* __restrict__ A, const float* __restrict__ Bw,
                       const float* __restrict__ bias, float* __restrict__ C,
                       int M, int N, int K, int Cin, int T) {
  __shared__ float As[16][65];
  __shared__ float Bs[16][68];
  const int tid = threadIdx.x;
  const int tm = tid >> 4, tn = tid & 15;
  const int m0 = blockIdx.x * 64, n0 = blockIdx.y * 64;
  const int la_m = tid >> 2, la_k = (tid & 3) * 4;
  const int lb_k = tid >> 4, lb_n = (tid & 15) * 4;
  const int p = m0 + la_m;
  int t = 0;
  if constexpr (IM2COL) t = p % T;

  float acc[4][4] = {};
  for (int k0 = 0; k0 < K; k0 += 16) {
#pragma unroll
    for (int i = 0; i < 4; ++i) {
      int k = k0 + la_k + i;
      float v;
      if constexpr (IM2COL) {
        int dt = (k >= Cin) + (k >= 2 * Cin);
        int tt = t + dt - 1;
        v = (tt >= 0 && tt < T) ? A[(long)p * Cin + (k - Cin)] : 0.f;
      } else {
        v = A[(long)p * K + k];
      }
      As[la_k + i][la_m] = v;
    }
#pragma unroll
    for (int i = 0; i < 4; ++i) {
      int n = n0 + lb_n + i;
      Bs[lb_k][lb_n + i] = (n < N) ? Bw[(long)(k0 + lb_k) * N + n] : 0.f;
    }
    __syncthreads();
#pragma unroll
    for (int kk = 0; kk < 16; ++kk) {
      float a[4], b[4];
#pragma unroll
      for (int i = 0; i < 4; ++i) a[i] = As[kk][tm * 4 + i];
#pragma unroll
      for (int j = 0; j < 4; ++j) b[j] = Bs[kk][tn * 4 + j];
#pragma unroll
      for (int i = 0; i < 4; ++i)
#pragma unroll
        for (int j = 0; j < 4; ++j) acc[i][j] += a[i] * b[j];
    }
    __syncthreads();
  }

  const int ncol = n0 + tn * 4;
  if (ncol < N) {
    float bv[4];
#pragma unroll
    for (int j = 0; j < 4; ++j) bv[j] = bias[ncol + j];
#pragma unroll
    for (int i = 0; i < 4; ++i) {
      int m = m0 + tm * 4 + i;
      float4 v;
      float* vv = (float*)&v;
#pragma unroll
      for (int j = 0; j < 4; ++j) {
        float u = acc[i][j] + bv[j];
        if constexpr (RELU) u = fmaxf(u, 0.f);
        vv[j] = u;
      }
      *(float4*)(C + (long)m * N + ncol) = v;
    }
  }
}

// ---------------------------------------------------------------------------
// fp32 GEMM 128x128, BK=16, 256 threads, 8x8 acc/thread (split fragments:
// rows tm*4 & 64+tm*4, cols tn*4 & 64+tn*4 -> <=2-way LDS bank aliasing).
// Requires M%128==0, N%128==0, K%16==0 (K%16 may stop early: K%16==0 here).
// ---------------------------------------------------------------------------
template<bool IM2COL, bool RELU>
__global__ void __launch_bounds__(256) gemm128(
    const float* __restrict__ A, const float* __restrict__ Bw,
    const float* __restrict__ bias, float* __restrict__ C,
    int M, int N, int K, int Cin, int T) {
  __shared__ float As[16][132];
  __shared__ float Bs[16][132];
  const int tid = threadIdx.x;
  const int m0 = blockIdx.x * 128, n0 = blockIdx.y * 128;
  const int tm = tid >> 4, tn = tid & 15;
  const int ar = tid >> 1, akc = (tid & 1) * 8;     // A: 128 rows x 16 k
  const int bk = tid >> 4, bnc = (tid & 15) * 8;    // B: 16 rows x 128 n
  const int p = m0 + ar;
  int t = 0;
  if constexpr (IM2COL) t = p % T;

  float acc[8][8] = {};
  for (int k0 = 0; k0 < K; k0 += 16) {
    float4 av0, av1;
    if constexpr (IM2COL) {
      int k = k0 + akc;                       // 8-group never straddles Cin blocks
      int dt = (k >= Cin) + (k >= 2 * Cin);
      int tt = t + dt - 1;
      const float* src = A + (long)p * Cin + (k - Cin);
      if (tt >= 0 && tt < T) { av0 = *(const float4*)src; av1 = *(const float4*)(src + 4); }
      else { av0 = {0.f,0.f,0.f,0.f}; av1 = {0.f,0.f,0.f,0.f}; }
    } else {
      const float* src = A + (long)p * K + k0 + akc;
      av0 = *(const float4*)src; av1 = *(const float4*)(src + 4);
    }
#pragma unroll
    for (int i = 0; i < 4; ++i) As[akc + i][ar] = ((const float*)&av0)[i];
#pragma unroll
    for (int i = 0; i < 4; ++i) As[akc + 4 + i][ar] = ((const float*)&av1)[i];
    {
      const float* src = Bw + (long)(k0 + bk) * N + n0 + bnc;
      *(float4*)(&Bs[bk][bnc])     = *(const float4*)src;
      *(float4*)(&Bs[bk][bnc + 4]) = *(const float4*)(src + 4);
    }
    __syncthreads();
#pragma unroll
    for (int kk = 0; kk < 16; ++kk) {
      float a[8], b[8];
      *(float4*)(a)     = *(const float4*)(&As[kk][tm * 4]);
      *(float4*)(a + 4) = *(const float4*)(&As[kk][64 + tm * 4]);
      *(float4*)(b)     = *(const float4*)(&Bs[kk][tn * 4]);
      *(float4*)(b + 4) = *(const float4*)(&Bs[kk][64 + tn * 4]);
#pragma unroll
      for (int i = 0; i < 8; ++i)
#pragma unroll
        for (int j = 0; j < 8; ++j) acc[i][j] += a[i] * b[j];
    }
    __syncthreads();
  }

  float bv[8];
#pragma unroll
  for (int j = 0; j < 8; ++j) bv[j] = bias[n0 + (j >> 2) * 64 + tn * 4 + (j & 3)];
#pragma unroll
  for (int i = 0; i < 8; ++i) {
    int m = m0 + (i >> 2) * 64 + tm * 4 + (i & 3);
    float4 v0, v1;
#pragma unroll
    for (int j = 0; j < 4; ++j) {
      float u0 = acc[i][j] + bv[j];
      float u1 = acc[i][4 + j] + bv[4 + j];
      if constexpr (RELU) { u0 = fmaxf(u0, 0.f); u1 = fmaxf(u1, 0.f); }
      ((float*)&v0)[j] = u0; ((float*)&v1)[j] = u1;
    }
    *(float4*)(C + (long)m * N + n0 + tn * 4)      = v0;
    *(float4*)(C + (long)m * N + n0 + 64 + tn * 4) = v1;
  }
}

// ---------------------------------------------------------------------------
// Row squared-norms: dst[row] = sum_c src[row][c]^2  (128 channels, wave/row)
// ---------------------------------------------------------------------------
__global__ void norms_k(const float* __restrict__ src, float* __restrict__ dst,
                        int rows) {
  int gw = (blockIdx.x * blockDim.x + threadIdx.x) >> 6;
  int lane = threadIdx.x & 63;
  if (gw >= rows) return;
  const float* r = src + (long)gw * 128;
  float a = r[lane], b = r[lane + 64];
  float s = a * a + b * b;
#pragma unroll
  for (int o = 32; o; o >>= 1) s += __shfl_xor(s, o);
  if (lane == 0) dst[gw] = s;
}

// ---------------------------------------------------------------------------
// Logits: L0[b][t][s] = -TEMP*(|q_bt|^2+|k_bs|^2-2 q.k); 128x128 tile BK=16.
// Both operands row-major [row][128] -> transposed LDS stores.
// ---------------------------------------------------------------------------
__global__ void __launch_bounds__(256) dist128(
    const float* __restrict__ q, const float* __restrict__ kmat,
    const float* __restrict__ q2, const float* __restrict__ k2,
    float* __restrict__ L0) {
  __shared__ float As[16][132];
  __shared__ float Bs[16][132];
  const int b = blockIdx.z;
  const int tid = threadIdx.x;
  const int m0 = blockIdx.x * 128, n0 = blockIdx.y * 128;
  const int tm = tid >> 4, tn = tid & 15;
  const int ar = tid >> 1, akc = (tid & 1) * 8;
  const float* Aq = q    + (long)b * TDE * CA;
  const float* Bk = kmat + (long)b * TEN * CA;

  float acc[8][8] = {};
  for (int k0 = 0; k0 < CA; k0 += 16) {
    float4 av0 = *(const float4*)(Aq + (long)(m0 + ar) * CA + k0 + akc);
    float4 av1 = *(const float4*)(Aq + (long)(m0 + ar) * CA + k0 + akc + 4);
    float4 bv0 = *(const float4*)(Bk + (long)(n0 + ar) * CA + k0 + akc);
    float4 bv1 = *(const float4*)(Bk + (long)(n0 + ar) * CA + k0 + akc + 4);
#pragma unroll
    for (int i = 0; i < 4; ++i) As[akc + i][ar] = ((const float*)&av0)[i];
#pragma unroll
    for (int i = 0; i < 4; ++i) As[akc + 4 + i][ar] = ((const float*)&av1)[i];
#pragma unroll
    for (int i = 0; i < 4; ++i) Bs[akc + i][ar] = ((const float*)&bv0)[i];
#pragma unroll
    for (int i = 0; i < 4; ++i) Bs[akc + 4 + i][ar] = ((const float*)&bv1)[i];
    __syncthreads();
#pragma unroll
    for (int kk = 0; kk < 16; ++kk) {
      float a[8], bb[8];
      *(float4*)(a)      = *(const float4*)(&As[kk][tm * 4]);
      *(float4*)(a + 4)  = *(const float4*)(&As[kk][64 + tm * 4]);
      *(float4*)(bb)     = *(const float4*)(&Bs[kk][tn * 4]);
      *(float4*)(bb + 4) = *(const float4*)(&Bs[kk][64 + tn * 4]);
#pragma unroll
      for (int i = 0; i < 8; ++i)
#pragma unroll
        for (int j = 0; j < 8; ++j) acc[i][j] += a[i] * bb[j];
    }
    __syncthreads();
  }

  float q2v[8], k2v[8];
#pragma unroll
  for (int i = 0; i < 8; ++i) q2v[i] = q2[b * TDE + m0 + (i >> 2) * 64 + tm * 4 + (i & 3)];
#pragma unroll
  for (int j = 0; j < 8; ++j) k2v[j] = k2[b * TEN + n0 + (j >> 2) * 64 + tn * 4 + (j & 3)];
#pragma unroll
  for (int i = 0; i < 8; ++i) {
    int m = m0 + (i >> 2) * 64 + tm * 4 + (i & 3);
    float4 v0, v1;
#pragma unroll
    for (int j = 0; j < 4; ++j) {
      ((float*)&v0)[j] = -TEMPC * (q2v[i] + k2v[j]     - 2.f * acc[i][j]);
      ((float*)&v1)[j] = -TEMPC * (q2v[i] + k2v[4 + j] - 2.f * acc[i][4 + j]);
    }
    *(float4*)(L0 + ((long)(b * TDE + m) * TEN) + n0 + tn * 4)      = v0;
    *(float4*)(L0 + ((long)(b * TDE + m) * TEN) + n0 + 64 + tn * 4) = v1;
  }
}

// ---------------------------------------------------------------------------
// Softmax stage (unchanged from round 1)
// ---------------------------------------------------------------------------
__global__ void softmax_k(float* __restrict__ out0, float* __restrict__ out1,
                          const float* __restrict__ priors) {
  __shared__ float Ls[16][513];
  __shared__ float Ps[16][257];
  __shared__ float red1[16];
  __shared__ float red2[16];
  const int b = blockIdx.y;
  const int t0 = blockIdx.x * 16;
  const int tid = threadIdx.x;
  const long base = ((long)b * TDE + t0) * TEN;

  for (int i = tid; i < 16 * 512; i += 256) Ls[i >> 9][i & 511] = out0[base + i];
  __syncthreads();

  const int wave = tid >> 6, lane = tid & 63;
#pragma unroll
  for (int rr = 0; rr < 4; ++rr) {
    int r = wave * 4 + rr;
    float m = -INFINITY;
    for (int i = 0; i < 8; ++i) m = fmaxf(m, Ls[r][lane + 64 * i]);
    for (int o = 32; o; o >>= 1) m = fmaxf(m, __shfl_xor(m, o));
    float sum = 0.f;
    for (int i = 0; i < 8; ++i) sum += expf(Ls[r][lane + 64 * i] - m);
    for (int o = 32; o; o >>= 1) sum += __shfl_xor(sum, o);
    if (lane == 0) red1[r] = m + logf(sum);
  }
  __syncthreads();

  for (int h = 0; h < 2; ++h) {
    for (int i = tid; i < 16 * 256; i += 256) {
      int s = (i >> 4) + h * 256, tt = i & 15;
      Ps[tt][i >> 4] = priors[((long)b * TEN + s) * TDE + t0 + tt];
    }
    __syncthreads();
    for (int i = tid; i < 16 * 256; i += 256) {
      int r = i >> 8, sl = i & 255, s = sl + h * 256;
      float alp = Ls[r][s] - red1[r] + logf(Ps[r][sl] + 1e-8f);
      Ls[r][s] = alp;
      out0[base + r * 512 + s] = alp;
    }
    __syncthreads();
  }

#pragma unroll
  for (int rr = 0; rr < 4; ++rr) {
    int r = wave * 4 + rr;
    float m = -INFINITY;
    for (int i = 0; i < 8; ++i) m = fmaxf(m, Ls[r][lane + 64 * i]);
    for (int o = 32; o; o >>= 1) m = fmaxf(m, __shfl_xor(m, o));
    float sum = 0.f;
    for (int i = 0; i < 8; ++i) sum += expf(Ls[r][lane + 64 * i] - m);
    for (int o = 32; o; o >>= 1) sum += __shfl_xor(sum, o);
    if (lane == 0) red2[r] = m + logf(sum);
  }
  __syncthreads();

  for (int i = tid; i < 16 * 512; i += 256) {
    int r = i >> 9, s = i & 511;
    out1[base + i] = expf(Ls[r][s] - red2[r]);
  }
}

// ---------------------------------------------------------------------------
// Monotonic alignment search v2.
// Forward: 8-step ping-pong register prefetch (hides HBM latency); per-step
// updates computed descending-i so all 8 are independent (no carry chain);
// loop split at j=512 to drop the activity predicate on 75% of steps.
// Dirs packed 4 steps/uint -> coalesced 256B stores.
// Backward: 16-step groups; idx drops <=15/group so a 3-byte window covers
// all bit reads -> 12 independent dword loads/group, register resolve.
// ---------------------------------------------------------------------------
template<bool MASKED>
__device__ __forceinline__ unsigned mas_step(float (&v)[8], const float4& b0,
                                             const float4& b1, int j, int lane,
                                             int xbase) {
  float a[8] = {b0.x, b0.y, b0.z, b0.w, b1.x, b1.y, b1.z, b1.w};
  float prev = __shfl_up(v[7], 1);
  if (lane == 0) prev = -INFINITY;
  unsigned dir = 0;
#pragma unroll
  for (int i = 7; i >= 1; --i) {          // descending: v[i-1] still OLD
    bool mm = v[i] >= v[i - 1];
    float vm = mm ? v[i] : v[i - 1];
    dir |= ((unsigned)mm) << i;
    float nv = vm + a[i];
    v[i] = (!MASKED || (xbase + i <= j)) ? nv : -INFINITY;
  }
  bool mm0 = v[0] >= prev;
  float vm0 = mm0 ? v[0] : prev;
  dir |= (unsigned)mm0;
  v[0] = (!MASKED || (xbase <= j)) ? (vm0 + a[0]) : -INFINITY;
  return dir;
}

__global__ void __launch_bounds__(64) mas_k(const float* __restrict__ attn,
                                            unsigned* __restrict__ dirs32,
                                            int* __restrict__ pathidx) {
  const int b = blockIdx.x;
  const int lane = threadIdx.x;
  const int xbase = lane * 8;
  float v[8];
#pragma unroll
  for (int i = 0; i < 8; ++i) v[i] = 0.f;
  const float* arow = attn + (long)b * TDE * TEN + xbase;
  unsigned* dbase = dirs32 + (long)b * (TDE / 4) * 64;

  float4 PA[8][2], PB[8][2];

#define LOADG(BUF, JO)                                                   \
  {                                                                      \
    _Pragma("unroll") for (int s = 0; s < 8; ++s) {                      \
      BUF[s][0] = *(const float4*)(arow + (long)((JO) + s) * TEN);       \
      BUF[s][1] = *(const float4*)(arow + (long)((JO) + s) * TEN + 4);   \
    }                                                                    \
  }
#define C8(BUF, JO, MSK)                                                 \
  {                                                                      \
    unsigned dw = 0;                                                     \
    _Pragma("unroll") for (int s = 0; s < 8; ++s) {                      \
      unsigned dir = mas_step<MSK>(v, BUF[s][0], BUF[s][1], (JO) + s,    \
                                   lane, xbase);                         \
      dw |= dir << (8 * (s & 3));                                        \
      if ((s & 3) == 3) {                                                \
        dbase[(((JO) + s) >> 2) * 64 + lane] = dw;                       \
        dw = 0;                                                          \
      }                                                                  \
    }                                                                    \
  }

  LOADG(PA, 0);
  for (int jo = 0; jo < 512; jo += 16) {
    LOADG(PB, jo + 8);
    C8(PA, jo, true);
    LOADG(PA, jo + 16);
    C8(PB, jo + 8, true);
  }
  for (int jo = 512; jo < 2048; jo += 16) {
    LOADG(PB, jo + 8);
    C8(PA, jo, false);
    LOADG(PA, jo + 16);            // final iter reads past row 2047: valid mem
    C8(PB, jo + 8, false);
  }
#undef LOADG
#undef C8

  __syncthreads();                 // drains vmcnt -> dirs visible to lane 0

  if (lane == 0) {
    int idx = TEN - 1;
    for (int g = 127; g >= 0; --g) {
      const int j0 = g * 16;
      const int hi = idx;
      int wb = (hi >> 3) - 2;
      if (wb < 0) wb = 0;
      unsigned w[4][3];
#pragma unroll
      for (int pp = 0; pp < 4; ++pp)
#pragma unroll
        for (int cc = 0; cc < 3; ++cc)
          w[pp][cc] = dbase[((j0 >> 2) + pp) * 64 + wb + cc];
#pragma unroll
      for (int k = 15; k >= 0; --k) {
        int j = j0 + k;
        pathidx[b * TDE + j] = idx;
        unsigned sh = 8u * (k & 3);
        unsigned b0 = (w[k >> 2][0] >> sh) & 0xffu;
        unsigned b1 = (w[k >> 2][1] >> sh) & 0xffu;
        unsigned b2 = (w[k >> 2][2] >> sh) & 0xffu;
        unsigned wd = b0 | (b1 << 8) | (b2 << 16);
        int d = (wd >> (idx - wb * 8)) & 1;
        idx += d - 1;
        if (idx < 0) idx = 0;
      }
    }
  }
}

// ---------------------------------------------------------------------------
// out2[b][t][s] = (s == pathidx[b][t]) as float (mas transposed)
// ---------------------------------------------------------------------------
__global__ void onehot_k(const int* __restrict__ pathidx, float* __restrict__ out2) {
  long idx = (long)blockIdx.x * blockDim.x + threadIdx.x;
  const long total4 = (long)BB * TDE * TEN / 4;
  if (idx >= total4) return;
  long row = idx >> 7;
  int s0 = (int)(idx & 127) * 4;
  int p = pathidx[row];
  float4 v;
  v.x = (s0 == p) ? 1.f : 0.f;
  v.y = (s0 + 1 == p) ? 1.f : 0.f;
  v.z = (s0 + 2 == p) ? 1.f : 0.f;
  v.w = (s0 + 3 == p) ? 1.f : 0.f;
  ((float4*)out2)[idx] = v;
}

// ---------------------------------------------------------------------------
// durations[b][x] = #{ j : pathidx[b][j] == x }  (written as float)
// ---------------------------------------------------------------------------
__global__ void dur_k(const int* __restrict__ pathidx, float* __restrict__ out3) {
  __shared__ int cnt[TEN];
  const int b = blockIdx.x, tid = threadIdx.x;
  cnt[tid] = 0;
  __syncthreads();
  for (int j = tid; j < TDE; j += 512) atomicAdd(&cnt[pathidx[b * TDE + j]], 1);
  __syncthreads();
  out3[b * TEN + tid] = (float)cnt[tid];
}

// ---------------------------------------------------------------------------
extern "C" void kernel_launch(void* const* d_in, const int* in_sizes, int n_in,
                              void* d_out, int out_size, void* d_ws, size_t ws_size,
                              hipStream_t stream) {
  (void)in_sizes; (void)n_in; (void)out_size; (void)ws_size;
  const float* x      = (const float*)d_in[0];
  const float* y      = (const float*)d_in[1];
  const float* priors = (const float*)d_in[4];
  const float* kw1 = (const float*)d_in[5];
  const float* kb1 = (const float*)d_in[6];
  const float* kw2 = (const float*)d_in[7];
  const float* kb2 = (const float*)d_in[8];
  const float* qw1 = (const float*)d_in[9];
  const float* qb1 = (const float*)d_in[10];
  const float* qw2 = (const float*)d_in[11];
  const float* qb2 = (const float*)d_in[12];
  const float* qw3 = (const float*)d_in[13];
  const float* qb3 = (const float*)d_in[14];

  const long OSZ = (long)BB * TDE * TEN;
  float* out0 = (float*)d_out;
  float* out1 = out0 + OSZ;
  float* out2 = out1 + OSZ;
  float* out3 = out2 + OSZ;

  char* ws = (char*)d_ws;
  float* wk1t = (float*)(ws + 0);
  float* wk2t = (float*)(ws + 6291456);
  float* wq1t = (float*)(ws + 6815744);
  float* wq2t = (float*)(ws + 6969344);
  float* wq3t = (float*)(ws + 7020544);
  float* kbuf = (float*)(ws + 7061504);
  float* qbuf = (float*)(ws + 15450112);
  float* q2   = (float*)(ws + 49004544);
  float* k2   = (float*)(ws + 49266688);
  int*   pidx = (int*)(ws + 49332224);
  unsigned* dirs32 = (unsigned*)(ws + 49594368);   // 4,194,304 B
  float* hk   = (float*)(ws + 53788672);
  float* hq1  = hk;
  float* qmid = (float*)(ws + 53788672 + 41943040);

  transpose_w<<<dim3(1024), dim3(256), 0, stream>>>(kw1, wk1t, CK, 2 * CK, 3);
  transpose_w<<<dim3(512),  dim3(256), 0, stream>>>(kw2, wk2t, 2 * CK, CA, 1);
  transpose_w<<<dim3(150),  dim3(256), 0, stream>>>(qw1, wq1t, CQ, 2 * CQ, 3);
  transpose_w<<<dim3(50),   dim3(256), 0, stream>>>(qw2, wq2t, 2 * CQ, CQ, 1);
  transpose_w<<<dim3(40),   dim3(256), 0, stream>>>(qw3, wq3t, CQ, CA, 1);

  // key path
  gemm128<true, true><<<dim3(128, 8), dim3(256), 0, stream>>>(
      x, wk1t, kb1, hk, 16384, 1024, 1536, CK, TEN);
  gemm128<false, false><<<dim3(128, 1), dim3(256), 0, stream>>>(
      hk, wk2t, kb2, kbuf, 16384, 128, 1024, 0, 0);

  // query path
  gemm_k<true, true><<<dim3(65536 / 64, 3), dim3(256), 0, stream>>>(
      y, wq1t, qb1, hq1, 65536, 160, 240, CQ, TDE);
  gemm_k<false, true><<<dim3(65536 / 64, 2), dim3(256), 0, stream>>>(
      hq1, wq2t, qb2, qmid, 65536, 80, 160, 0, 0);
  gemm128<false, false><<<dim3(512, 1), dim3(256), 0, stream>>>(
      qmid, wq3t, qb3, qbuf, 65536, 128, 80, 0, 0);

  norms_k<<<dim3(65536 / 4), dim3(256), 0, stream>>>(qbuf, q2, 65536);
  norms_k<<<dim3(16384 / 4), dim3(256), 0, stream>>>(kbuf, k2, 16384);

  dist128<<<dim3(16, 4, 32), dim3(256), 0, stream>>>(qbuf, kbuf, q2, k2, out0);

  softmax_k<<<dim3(128, 32), dim3(256), 0, stream>>>(out0, out1, priors);

  mas_k<<<dim3(32), dim3(64), 0, stream>>>(out1, dirs32, pidx);

  onehot_k<<<dim3(32768), dim3(256), 0, stream>>>(pidx, out2);
  dur_k<<<dim3(32), dim3(512), 0, stream>>>(pidx, out3);
}